// Round 18
// baseline (82.252 us; speedup 1.0000x reference)
//
#include <hip/hip_runtime.h>
#include <stdint.h>

#define SHAPE    512
#define DEPTH    9
#define NCELLS   (SHAPE * SHAPE)
#define NB       8                 // batches (== XCD count: b = blk&7 pins batch->XCD)
#define RANGES   1024              // cell ranges per batch
#define CR       (NCELLS / RANGES) // 256 cells per range
#define CRSHIFT  8
#define CAP      512               // bucket capacity (mean 195, ~22 sigma headroom)
#define CAPSHIFT 9
#define NCHUNK   64                // point chunks per batch (R13-best)
#define SENT     0xFFFFFFFFu
#define EMIT     ((CR * DEPTH) / 256)   // 9 emit iterations per thread

typedef float f32x4 __attribute__((ext_vector_type(4)));

// ---- fast path: single-pass privatized binning + LDS cascade group ----

__global__ void zero_heads(unsigned* __restrict__ h, int n) {
    int t = blockIdx.x * blockDim.x + threadIdx.x;
    if (t < n) h[t] = 0u;
}

// Per-block LDS histogram over the 1024 ranges, ONE global atomicAdd per
// (block,range) reserving a dense bucket segment, then direct scatter of
// packed keys (index<<8 | cell_local, 4 B) through LDS cursors. Bucket order
// is arbitrary — group's cascade result depends only on the key multiset.
// 1D grid, b = blk&7: all of batch b's buckets live on XCD b's L2, which
// group (same mapping) then reads on-die.
__global__ __launch_bounds__(512) void bin_kernel(const float4* __restrict__ pts,
                                                  unsigned* __restrict__ headcnt,
                                                  unsigned* __restrict__ bktE,
                                                  int nPerB, int chSz) {
    __shared__ unsigned h[RANGES];
    int b = blockIdx.x & (NB - 1);
    int c = blockIdx.x >> 3;
    for (int r = threadIdx.x; r < RANGES; r += 512) h[r] = 0u;
    __syncthreads();

    int i0 = c * chSz;
    int i1 = i0 + chSz; if (i1 > nPerB) i1 = nPerB;
    const float4* pb = pts + (size_t)b * nPerB;

    for (int i = i0 + threadIdx.x; i < i1; i += 512) {
        float4 p = pb[i];
        if (p.x == 0.f && p.y == 0.f && p.z == 0.f && p.w == 0.f) continue;
        int xi = (int)(p.x * (float)SHAPE);   // trunc == reference astype(int32)
        int yi = (int)(p.y * (float)SHAPE);
        unsigned cell = (unsigned)(xi * SHAPE + yi);
        if (cell >= (unsigned)NCELLS) continue;
        atomicAdd(&h[cell >> CRSHIFT], 1u);
    }
    __syncthreads();

    for (int r = threadIdx.x; r < RANGES; r += 512) {
        unsigned n = h[r];
        unsigned bucket = (unsigned)(b * RANGES + r);
        unsigned base = n ? atomicAdd(&headcnt[bucket], n) : 0u;
        h[r] = (bucket << CAPSHIFT) + base;            // absolute write cursor
    }
    __syncthreads();

    for (int i = i0 + threadIdx.x; i < i1; i += 512) {
        float4 p = pb[i];
        if (p.x == 0.f && p.y == 0.f && p.z == 0.f && p.w == 0.f) continue;
        int xi = (int)(p.x * (float)SHAPE);
        int yi = (int)(p.y * (float)SHAPE);
        unsigned cell = (unsigned)(xi * SHAPE + yi);
        if (cell >= (unsigned)NCELLS) continue;
        unsigned r = cell >> CRSHIFT;
        unsigned pos = atomicAdd(&h[r], 1u);
        unsigned bucket = (unsigned)(b * RANGES) + r;
        if (pos < ((bucket + 1u) << CAPSHIFT))         // bucket overflow dropped
            bktE[pos] = ((unsigned)i << CRSHIFT) | (cell & (CR - 1));
    }
}

// One block per (batch, range), b = blk&7 (XCD-pinned). Top-9-min insertion
// per cell via LDS atomicMin cascade on the packed key (key order == original
// index order, unique -> deterministic across replays). bktE is read with
// NONTEMPORAL loads (read-once data, keeps the reused pts slice L2-resident).
// Emit is split 3x3: 3 gathers per vmcnt drain (ILP) at only 12 pv-VGPRs
// (occupancy ~32 waves/CU vs 20 for the 9-deep batch).
__global__ __launch_bounds__(256) void group_kernel(const unsigned* __restrict__ headcnt,
                                                    const unsigned* __restrict__ bktE,
                                                    const float4* __restrict__ pts,
                                                    float4* __restrict__ out,
                                                    int nPerB) {
    __shared__ unsigned slots[CR * DEPTH];   // 2304 u32 = 9 KB
    int blk = blockIdx.x;
    int b = blk & (NB - 1);                  // batch -> XCD pin
    int r = blk >> 3;                        // range within batch
    int gblk = b * RANGES + r;

    unsigned n = headcnt[gblk];              // issue early; consumed after init

    uint4* s4 = (uint4*)slots;
    for (int k = threadIdx.x; k < (CR * DEPTH) / 4; k += 256)
        s4[k] = make_uint4(SENT, SENT, SENT, SENT);
    __syncthreads();

    if (n > CAP) n = CAP;
    size_t base = (size_t)gblk << CAPSHIFT;

    for (unsigned t = threadIdx.x; t < n; t += 256) {
        unsigned v = __builtin_nontemporal_load(&bktE[base + t]);  // read-once
        unsigned* s = &slots[(v & (CR - 1)) * DEPTH];
#pragma unroll
        for (int d = 0; d < DEPTH; ++d) {
            unsigned old = atomicMin(&s[d], v);
            if (old == SENT) break;                   // empty slot claimed
            v = (v > old) ? v : old;                  // displaced max continues
        }
    }
    __syncthreads();

    const float4* pb = pts + (size_t)b * nPerB;
    float4* ob = out + ((size_t)b * NCELLS + ((size_t)r << CRSHIFT)) * DEPTH;

    // all 9 slot keys -> registers (static indices after unroll)
    unsigned key[EMIT];
#pragma unroll
    for (int k = 0; k < EMIT; ++k)
        key[k] = slots[threadIdx.x + k * 256];

    // emit in 3 batches of 3: 3 back-to-back gathers, then 3 NT stores
#pragma unroll
    for (int g = 0; g < 3; ++g) {
        unsigned k0 = key[g * 3 + 0], k1 = key[g * 3 + 1], k2 = key[g * 3 + 2];
        float4 p0, p1, p2;                   // named regs (rule-#20 safe)
        if (k0 != SENT) p0 = pb[k0 >> CRSHIFT];
        if (k1 != SENT) p1 = pb[k1 >> CRSHIFT];
        if (k2 != SENT) p2 = pb[k2 >> CRSHIFT];

        f32x4 rv0 = (f32x4){0.f, 0.f, 0.f, 0.f};
        f32x4 rv1 = rv0, rv2 = rv0;
        if (k0 != SENT) {
            float sx = p0.x * (float)SHAPE, sy = p0.y * (float)SHAPE;
            rv0 = (f32x4){sx - truncf(sx), sy - truncf(sy), p0.z, p0.w};
        }
        if (k1 != SENT) {
            float sx = p1.x * (float)SHAPE, sy = p1.y * (float)SHAPE;
            rv1 = (f32x4){sx - truncf(sx), sy - truncf(sy), p1.z, p1.w};
        }
        if (k2 != SENT) {
            float sx = p2.x * (float)SHAPE, sy = p2.y * (float)SHAPE;
            rv2 = (f32x4){sx - truncf(sx), sy - truncf(sy), p2.z, p2.w};
        }
        __builtin_nontemporal_store(rv0, (f32x4*)&ob[threadIdx.x + (g * 3 + 0) * 256]);
        __builtin_nontemporal_store(rv1, (f32x4*)&ob[threadIdx.x + (g * 3 + 1) * 256]);
        __builtin_nontemporal_store(rv2, (f32x4*)&ob[threadIdx.x + (g * 3 + 2) * 256]);
    }
}

// ---- fallback path (stage indices inside d_out; used only if ws too small
//      or per-batch point count exceeds the 18-bit key budget) ----

__global__ void init_kernel(uint4* __restrict__ A, int nVec4) {
    int tid = blockIdx.x * blockDim.x + threadIdx.x;
    if (tid < nVec4) A[tid] = make_uint4(SENT, SENT, SENT, SENT);
}

__global__ void cascade_kernel(const float4* __restrict__ pts,
                               unsigned* A, int nTotal, int nPerB) {
    int tid = blockIdx.x * blockDim.x + threadIdx.x;
    if (tid >= nTotal) return;
    int b = tid / nPerB;
    int i = tid - b * nPerB;
    float4 p = pts[tid];
    if (p.x == 0.f && p.y == 0.f && p.z == 0.f && p.w == 0.f) return;
    int xi = (int)(p.x * (float)SHAPE), yi = (int)(p.y * (float)SHAPE);
    int cell = xi * SHAPE + yi;
    if ((unsigned)cell >= (unsigned)NCELLS) return;
    unsigned v = (unsigned)i;
    unsigned* base = A + (size_t)(b * NCELLS + cell) * (DEPTH * 4);
#pragma unroll
    for (int s = 0; s < DEPTH; ++s) {
        unsigned old = atomicMin(base + s * 4, v);
        if (old == SENT) break;
        v = (v > old) ? v : old;
    }
}

__global__ void write_kernel(const float4* __restrict__ pts,
                             const unsigned* A, float4* out, int nSlots, int nPerB) {
    int tid = blockIdx.x * blockDim.x + threadIdx.x;
    if (tid >= nSlots) return;
    unsigned idx = A[(size_t)tid * 4];
    float4 r = make_float4(0.f, 0.f, 0.f, 0.f);
    if (idx < (unsigned)nPerB) {
        int b = tid / (NCELLS * DEPTH);
        float4 p = pts[(size_t)b * nPerB + idx];
        float sx = p.x * (float)SHAPE, sy = p.y * (float)SHAPE;
        r.x = sx - truncf(sx); r.y = sy - truncf(sy);
        r.z = p.z; r.w = p.w;
    }
    out[tid] = r;
}

extern "C" void kernel_launch(void* const* d_in, const int* in_sizes, int n_in,
                              void* d_out, int out_size, void* d_ws, size_t ws_size,
                              hipStream_t stream) {
    const float4* pts = (const float4*)d_in[0];

    int total = in_sizes[0];               // 8*200000*4
    int nPerB = total / (NB * 4);          // 200,000

    int nBuckets = NB * RANGES;                                       // 8192
    size_t eBytes = (size_t)nBuckets * CAP * sizeof(unsigned);        // 16 MB
    size_t hBytes = (size_t)nBuckets * sizeof(unsigned);              // 32 KB
    size_t need = eBytes + hBytes;

    bool fast = (ws_size >= need) && (nPerB <= (1 << 18));
    if (fast) {
        unsigned* bktE    = (unsigned*)d_ws;
        unsigned* headcnt = (unsigned*)((char*)d_ws + eBytes);

        int chSz = (nPerB + NCHUNK - 1) / NCHUNK;     // 3125

        zero_heads<<<(nBuckets + 255) / 256, 256, 0, stream>>>(headcnt, nBuckets);

        bin_kernel<<<NCHUNK * NB, 512, 0, stream>>>(pts, headcnt, bktE, nPerB, chSz);

        group_kernel<<<RANGES * NB, 256, 0, stream>>>(headcnt, bktE, pts,
                                                      (float4*)d_out, nPerB);
    } else {
        int nPts   = NB * nPerB;
        int nSlots = NB * NCELLS * DEPTH;
        unsigned* A = (unsigned*)d_out;
        int initVec4 = out_size / 4;
        init_kernel<<<(initVec4 + 255) / 256, 256, 0, stream>>>((uint4*)A, initVec4);
        cascade_kernel<<<(nPts + 255) / 256, 256, 0, stream>>>(pts, A, nPts, nPerB);
        write_kernel<<<(nSlots + 255) / 256, 256, 0, stream>>>(
            pts, A, (float4*)d_out, nSlots, nPerB);
    }
}

// Round 19
// 78.518 us; speedup vs baseline: 1.0476x; 1.0476x over previous
//
#include <hip/hip_runtime.h>
#include <stdint.h>

#define SHAPE    512
#define DEPTH    9
#define NCELLS   (SHAPE * SHAPE)
#define NB       8                 // batches (== XCD count: b = blk&7 pins batch->XCD)
#define RANGES   1024              // cell ranges per batch
#define CR       (NCELLS / RANGES) // 256 cells per range
#define CRSHIFT  8
#define CAP      512               // bucket capacity (mean 195, ~22 sigma headroom)
#define CAPSHIFT 9
#define NCHUNK   64                // point chunks per batch
#define SENT     0xFFFFFFFFu
#define EMIT     ((CR * DEPTH) / 256)   // 9 emit iterations per thread

typedef float f32x4 __attribute__((ext_vector_type(4)));

// ---- fast path: single-pass privatized binning + LDS cascade group ----
// CHAMPION CONFIG (79.0 us, round 12/13). All structural perturbations A/B'd
// flat or negative: range-pairing (83.0), plain stores (80.8), point-carrying
// buckets (96.0), 2x bin TLP (80.3), NT bktE loads + 3x3 emit split (82.3).

__global__ void zero_heads(unsigned* __restrict__ h, int n) {
    int t = blockIdx.x * blockDim.x + threadIdx.x;
    if (t < n) h[t] = 0u;
}

// Per-block LDS histogram over the 1024 ranges, ONE global atomicAdd per
// (block,range) reserving a dense bucket segment, then direct scatter of
// packed keys (index<<8 | cell_local, 4 B) through LDS cursors. Bucket order
// is arbitrary — group's cascade result depends only on the key multiset.
// 1D grid, b = blk&7: all of batch b's buckets live on XCD b's L2, which
// group (same mapping) then reads on-die.
__global__ __launch_bounds__(512) void bin_kernel(const float4* __restrict__ pts,
                                                  unsigned* __restrict__ headcnt,
                                                  unsigned* __restrict__ bktE,
                                                  int nPerB, int chSz) {
    __shared__ unsigned h[RANGES];
    int b = blockIdx.x & (NB - 1);
    int c = blockIdx.x >> 3;
    for (int r = threadIdx.x; r < RANGES; r += 512) h[r] = 0u;
    __syncthreads();

    int i0 = c * chSz;
    int i1 = i0 + chSz; if (i1 > nPerB) i1 = nPerB;
    const float4* pb = pts + (size_t)b * nPerB;

    for (int i = i0 + threadIdx.x; i < i1; i += 512) {
        float4 p = pb[i];
        if (p.x == 0.f && p.y == 0.f && p.z == 0.f && p.w == 0.f) continue;
        int xi = (int)(p.x * (float)SHAPE);   // trunc == reference astype(int32)
        int yi = (int)(p.y * (float)SHAPE);
        unsigned cell = (unsigned)(xi * SHAPE + yi);
        if (cell >= (unsigned)NCELLS) continue;
        atomicAdd(&h[cell >> CRSHIFT], 1u);
    }
    __syncthreads();

    for (int r = threadIdx.x; r < RANGES; r += 512) {
        unsigned n = h[r];
        unsigned bucket = (unsigned)(b * RANGES + r);
        unsigned base = n ? atomicAdd(&headcnt[bucket], n) : 0u;
        h[r] = (bucket << CAPSHIFT) + base;            // absolute write cursor
    }
    __syncthreads();

    for (int i = i0 + threadIdx.x; i < i1; i += 512) {
        float4 p = pb[i];
        if (p.x == 0.f && p.y == 0.f && p.z == 0.f && p.w == 0.f) continue;
        int xi = (int)(p.x * (float)SHAPE);
        int yi = (int)(p.y * (float)SHAPE);
        unsigned cell = (unsigned)(xi * SHAPE + yi);
        if (cell >= (unsigned)NCELLS) continue;
        unsigned r = cell >> CRSHIFT;
        unsigned pos = atomicAdd(&h[r], 1u);
        unsigned bucket = (unsigned)(b * RANGES) + r;
        if (pos < ((bucket + 1u) << CAPSHIFT))         // bucket overflow dropped
            bktE[pos] = ((unsigned)i << CRSHIFT) | (cell & (CR - 1));
    }
}

// One block per (batch, range), b = blk&7 (XCD-pinned). Top-9-min insertion
// per cell via LDS atomicMin cascade on the packed key (key order == original
// index order, unique -> deterministic across replays). Batched emit (EMIT=9):
// all keys read, all predicated gathers issue back-to-back (single amortized
// vmcnt drain), then 9 coalesced NT stores.
__global__ __launch_bounds__(256) void group_kernel(const unsigned* __restrict__ headcnt,
                                                    const unsigned* __restrict__ bktE,
                                                    const float4* __restrict__ pts,
                                                    float4* __restrict__ out,
                                                    int nPerB) {
    __shared__ unsigned slots[CR * DEPTH];   // 2304 u32 = 9 KB
    int blk = blockIdx.x;
    int b = blk & (NB - 1);                  // batch -> XCD pin
    int r = blk >> 3;                        // range within batch
    int gblk = b * RANGES + r;

    uint4* s4 = (uint4*)slots;
    for (int k = threadIdx.x; k < (CR * DEPTH) / 4; k += 256)
        s4[k] = make_uint4(SENT, SENT, SENT, SENT);
    __syncthreads();

    unsigned n = headcnt[gblk];
    if (n > CAP) n = CAP;
    size_t base = (size_t)gblk << CAPSHIFT;

    for (unsigned t = threadIdx.x; t < n; t += 256) {
        unsigned v = bktE[base + t];
        unsigned* s = &slots[(v & (CR - 1)) * DEPTH];
#pragma unroll
        for (int d = 0; d < DEPTH; ++d) {
            unsigned old = atomicMin(&s[d], v);
            if (old == SENT) break;                   // empty slot claimed
            v = (v > old) ? v : old;                  // displaced max continues
        }
    }
    __syncthreads();

    const float4* pb = pts + (size_t)b * nPerB;
    float4* ob = out + ((size_t)b * NCELLS + ((size_t)r << CRSHIFT)) * DEPTH;

    // phase 1: all 9 slot keys -> registers (static indices after unroll)
    unsigned key[EMIT];
#pragma unroll
    for (int k = 0; k < EMIT; ++k)
        key[k] = slots[threadIdx.x + k * 256];

    // phase 2: all 9 gathers issue back-to-back (exec-masked, no branches)
    float4 pv[EMIT];
#pragma unroll
    for (int k = 0; k < EMIT; ++k)
        if (key[k] != SENT) pv[k] = pb[key[k] >> CRSHIFT];

    // phase 3: compute + streaming NT stores
#pragma unroll
    for (int k = 0; k < EMIT; ++k) {
        f32x4 rv = (f32x4){0.f, 0.f, 0.f, 0.f};
        if (key[k] != SENT) {
            float sx = pv[k].x * (float)SHAPE;
            float sy = pv[k].y * (float)SHAPE;
            rv.x = sx - truncf(sx);
            rv.y = sy - truncf(sy);
            rv.z = pv[k].z;
            rv.w = pv[k].w;
        }
        __builtin_nontemporal_store(rv, (f32x4*)&ob[threadIdx.x + k * 256]);
    }
}

// ---- fallback path (stage indices inside d_out; used only if ws too small
//      or per-batch point count exceeds the 18-bit key budget) ----

__global__ void init_kernel(uint4* __restrict__ A, int nVec4) {
    int tid = blockIdx.x * blockDim.x + threadIdx.x;
    if (tid < nVec4) A[tid] = make_uint4(SENT, SENT, SENT, SENT);
}

__global__ void cascade_kernel(const float4* __restrict__ pts,
                               unsigned* A, int nTotal, int nPerB) {
    int tid = blockIdx.x * blockDim.x + threadIdx.x;
    if (tid >= nTotal) return;
    int b = tid / nPerB;
    int i = tid - b * nPerB;
    float4 p = pts[tid];
    if (p.x == 0.f && p.y == 0.f && p.z == 0.f && p.w == 0.f) return;
    int xi = (int)(p.x * (float)SHAPE), yi = (int)(p.y * (float)SHAPE);
    int cell = xi * SHAPE + yi;
    if ((unsigned)cell >= (unsigned)NCELLS) return;
    unsigned v = (unsigned)i;
    unsigned* base = A + (size_t)(b * NCELLS + cell) * (DEPTH * 4);
#pragma unroll
    for (int s = 0; s < DEPTH; ++s) {
        unsigned old = atomicMin(base + s * 4, v);
        if (old == SENT) break;
        v = (v > old) ? v : old;
    }
}

__global__ void write_kernel(const float4* __restrict__ pts,
                             const unsigned* A, float4* out, int nSlots, int nPerB) {
    int tid = blockIdx.x * blockDim.x + threadIdx.x;
    if (tid >= nSlots) return;
    unsigned idx = A[(size_t)tid * 4];
    float4 r = make_float4(0.f, 0.f, 0.f, 0.f);
    if (idx < (unsigned)nPerB) {
        int b = tid / (NCELLS * DEPTH);
        float4 p = pts[(size_t)b * nPerB + idx];
        float sx = p.x * (float)SHAPE, sy = p.y * (float)SHAPE;
        r.x = sx - truncf(sx); r.y = sy - truncf(sy);
        r.z = p.z; r.w = p.w;
    }
    out[tid] = r;
}

extern "C" void kernel_launch(void* const* d_in, const int* in_sizes, int n_in,
                              void* d_out, int out_size, void* d_ws, size_t ws_size,
                              hipStream_t stream) {
    const float4* pts = (const float4*)d_in[0];

    int total = in_sizes[0];               // 8*200000*4
    int nPerB = total / (NB * 4);          // 200,000

    int nBuckets = NB * RANGES;                                       // 8192
    size_t eBytes = (size_t)nBuckets * CAP * sizeof(unsigned);        // 16 MB
    size_t hBytes = (size_t)nBuckets * sizeof(unsigned);              // 32 KB
    size_t need = eBytes + hBytes;

    bool fast = (ws_size >= need) && (nPerB <= (1 << 18));
    if (fast) {
        unsigned* bktE    = (unsigned*)d_ws;
        unsigned* headcnt = (unsigned*)((char*)d_ws + eBytes);

        int chSz = (nPerB + NCHUNK - 1) / NCHUNK;     // 3125

        zero_heads<<<(nBuckets + 255) / 256, 256, 0, stream>>>(headcnt, nBuckets);

        bin_kernel<<<NCHUNK * NB, 512, 0, stream>>>(pts, headcnt, bktE, nPerB, chSz);

        group_kernel<<<RANGES * NB, 256, 0, stream>>>(headcnt, bktE, pts,
                                                      (float4*)d_out, nPerB);
    } else {
        int nPts   = NB * nPerB;
        int nSlots = NB * NCELLS * DEPTH;
        unsigned* A = (unsigned*)d_out;
        int initVec4 = out_size / 4;
        init_kernel<<<(initVec4 + 255) / 256, 256, 0, stream>>>((uint4*)A, initVec4);
        cascade_kernel<<<(nPts + 255) / 256, 256, 0, stream>>>(pts, A, nPts, nPerB);
        write_kernel<<<(nSlots + 255) / 256, 256, 0, stream>>>(
            pts, A, (float4*)d_out, nSlots, nPerB);
    }
}